// Round 2
// baseline (778.746 us; speedup 1.0000x reference)
//
#include <hip/hip_runtime.h>
#include <math.h>

#define S_LEN 2048
#define ENC2  1024
#define DEC_H 1024
#define ATT   1024
#define BATCH 32

typedef __attribute__((ext_vector_type(8)))  short short8;
typedef __attribute__((ext_vector_type(16))) float f32x16;

// ws layout: WT bf16 [ATT][ENC2] at 0 (2 MB), dproj f32 [B][ATT] at 2 MB (128 KB)
#define DP_OFF (ATT * ENC2 * 2)

__device__ __forceinline__ unsigned short f2bf(float f) {
    unsigned int u = __float_as_uint(f);
    return (unsigned short)((u + 0x7FFFu + ((u >> 16) & 1u)) >> 16);  // RNE
}

__device__ __forceinline__ float tanh_fast(float x) {
    // tanh(x) = sign(x) * (1 - e) / (1 + e), e = exp(-2|x|)  — overflow-free
    float ax = fabsf(x);
    float e = __expf(-2.0f * ax);
    float t = (1.0f - e) / (1.0f + e);
    return copysignf(t, x);
}

// ---- WT[n][k] = bf16(W_enc[k][n]) : 32x32 LDS tile transpose ----
__global__ void k_wt(const float* __restrict__ W, unsigned short* __restrict__ WT) {
    __shared__ float tile[32][33];
    int bx = blockIdx.x * 32, by = blockIdx.y * 32;
    int tx = threadIdx.x, ty = threadIdx.y;           // block (32,8)
#pragma unroll
    for (int i = 0; i < 32; i += 8)
        tile[ty + i][tx] = W[(size_t)(by + ty + i) * ATT + (bx + tx)];
    __syncthreads();
#pragma unroll
    for (int i = 0; i < 32; i += 8)
        WT[(size_t)(bx + ty + i) * ENC2 + (by + tx)] = f2bf(tile[tx][ty + i]);
}

// ---- dproj[b][n] = dec[b]@W_dec[:,n] + b_dec[n] + b_enc[n] (f32 exact) ----
__global__ void k_dproj(const float* __restrict__ dec, const float* __restrict__ Wd,
                        const float* __restrict__ b_dec, const float* __restrict__ b_enc,
                        float* __restrict__ dp) {
    int n = blockIdx.x * 256 + threadIdx.x;
    int b = blockIdx.y;
    float acc = b_dec[n] + b_enc[n];
    const float* dh = dec + b * DEC_H;
#pragma unroll 8
    for (int k = 0; k < DEC_H; ++k)
        acc = fmaf(dh[k], Wd[(size_t)k * ATT + n], acc);
    dp[b * ATT + n] = acc;
}

// ---- energy[m] = w_e . tanh(enc[m]@W_enc + dproj[b]) + b_e ; mask ----
__launch_bounds__(512, 2)
__global__ void k_energy(const float* __restrict__ enc,          // [B*S][ENC2] f32
                         const short* __restrict__ WT,           // [ATT][ENC2] bf16
                         const float* __restrict__ dp,           // [B][ATT]
                         const float* __restrict__ w_e,
                         const float* __restrict__ b_e,
                         const int* __restrict__ mask,           // [B*S] bool->int32
                         float* __restrict__ energy)             // [B*S]
{
    __shared__ short As[64 * 1024];   // 128 KB bf16, XOR-swizzled
    float* e_lds = (float*)As;        // aliased: used only AFTER the MFMA loop

    const int tid = threadIdx.x;
    const int r0  = blockIdx.x * 64;
    const int b   = r0 >> 11;

    // stage A-tile: 64 rows x 1024 f32 -> bf16, swizzle byte^=((row&15)<<4)
    {
        const float* src = enc + (size_t)r0 * ENC2;
        char* smem = (char*)As;
        for (int u = tid; u < 8192; u += 512) {
            int row = u >> 7, slot = u & 127;
            const float* p = src + (size_t)row * ENC2 + slot * 8;
            float4 f0 = *(const float4*)p;
            float4 f1 = *(const float4*)(p + 4);
            short8 v;
            v[0] = (short)f2bf(f0.x); v[1] = (short)f2bf(f0.y);
            v[2] = (short)f2bf(f0.z); v[3] = (short)f2bf(f0.w);
            v[4] = (short)f2bf(f1.x); v[5] = (short)f2bf(f1.y);
            v[6] = (short)f2bf(f1.z); v[7] = (short)f2bf(f1.w);
            int dst = row * 2048 + ((slot * 16) ^ ((row & 15) << 4));
            *(short8*)(smem + dst) = v;
        }
    }
    __syncthreads();

    const int lane = tid & 63;
    const int wid  = tid >> 6;
    const int col  = lane & 31;
    const int hi   = lane >> 5;
    const int nw   = wid * 128;

    float dv[4], wv[4];
#pragma unroll
    for (int nf = 0; nf < 4; ++nf) {
        int n = nw + nf * 32 + col;
        dv[nf] = dp[b * ATT + n];
        wv[nf] = w_e[n];
    }

    f32x16 acc[2][4] = {};
    const int xr = (col & 15) << 4;
    const char* arow0 = (const char*)As + col * 2048;
    const char* arow1 = (const char*)As + (col + 32) * 2048;

    const short* wtp[4];
#pragma unroll
    for (int nf = 0; nf < 4; ++nf)
        wtp[nf] = WT + (size_t)(nw + nf * 32 + col) * ENC2 + hi * 8;

    short8 bcur[4], bnxt[4];
#pragma unroll
    for (int nf = 0; nf < 4; ++nf) bcur[nf] = *(const short8*)(wtp[nf]);

#pragma unroll 2
    for (int k = 0; k < 1024; k += 16) {
        int kn = (k + 16) & 1023;      // last iter wraps (harmless dead prefetch)
#pragma unroll
        for (int nf = 0; nf < 4; ++nf) bnxt[nf] = *(const short8*)(wtp[nf] + kn);
        int off = ((k * 2 + hi * 16) ^ xr);
        short8 a0 = *(const short8*)(arow0 + off);
        short8 a1 = *(const short8*)(arow1 + off);
#pragma unroll
        for (int nf = 0; nf < 4; ++nf) {
            acc[0][nf] = __builtin_amdgcn_mfma_f32_32x32x16_bf16(a0, bcur[nf], acc[0][nf], 0, 0, 0);
            acc[1][nf] = __builtin_amdgcn_mfma_f32_32x32x16_bf16(a1, bcur[nf], acc[1][nf], 0, 0, 0);
        }
#pragma unroll
        for (int nf = 0; nf < 4; ++nf) bcur[nf] = bnxt[nf];
    }

    // epilogue: tanh, dot with w_e, per-lane partials over 32 rows
    float ep[32];
#pragma unroll
    for (int mf = 0; mf < 2; ++mf)
#pragma unroll
        for (int reg = 0; reg < 16; ++reg) {
            float s = 0.0f;
#pragma unroll
            for (int nf = 0; nf < 4; ++nf)
                s = fmaf(wv[nf], tanh_fast(acc[mf][nf][reg] + dv[nf]), s);
            ep[mf * 16 + reg] = s;
        }

#pragma unroll
    for (int d = 1; d < 32; d <<= 1)
#pragma unroll
        for (int j = 0; j < 32; ++j)
            ep[j] += __shfl_xor(ep[j], d, 64);

    __syncthreads();                       // all waves done reading As
    if (tid < 64) e_lds[tid] = 0.0f;
    __syncthreads();

    if (col == 0) {
#pragma unroll
        for (int j = 0; j < 32; ++j) {
            int reg = j & 15;
            int row = (j >> 4) * 32 + (reg & 3) + 8 * (reg >> 2) + 4 * hi;
            atomicAdd(&e_lds[row], ep[j]);
        }
    }
    __syncthreads();

    if (tid < 64) {
        int m = r0 + tid;                    // m = b*S + s (flat)
        float e = e_lds[tid] + b_e[0];
        if (!mask[m]) e = -INFINITY;         // mask is int32 (bool -> int)
        energy[m] = e;
    }
}

// ---- softmax over S per batch, in place; also zero context region ----
__global__ void k_softmax(float* __restrict__ out) {
    int b = blockIdx.x, tid = threadIdx.x;   // 256 threads
    float* ew = out + BATCH * ATT + (size_t)b * S_LEN;
    float v[8];
#pragma unroll
    for (int i = 0; i < 8; ++i) v[i] = ew[i * 256 + tid];
    float m = v[0];
#pragma unroll
    for (int i = 1; i < 8; ++i) m = fmaxf(m, v[i]);
#pragma unroll
    for (int d = 1; d < 64; d <<= 1) m = fmaxf(m, __shfl_xor(m, d, 64));
    __shared__ float red[4], red2[4];
    int w = tid >> 6;
    if ((tid & 63) == 0) red[w] = m;
    __syncthreads();
    m = fmaxf(fmaxf(red[0], red[1]), fmaxf(red[2], red[3]));
    float s = 0.0f;
#pragma unroll
    for (int i = 0; i < 8; ++i) { v[i] = __expf(v[i] - m); s += v[i]; }
#pragma unroll
    for (int d = 1; d < 64; d <<= 1) s += __shfl_xor(s, d, 64);
    if ((tid & 63) == 0) red2[w] = s;
    __syncthreads();
    s = red2[0] + red2[1] + red2[2] + red2[3];
    float inv = 1.0f / s;
#pragma unroll
    for (int i = 0; i < 8; ++i) ew[i * 256 + tid] = v[i] * inv;
    float* ctx = out + (size_t)b * ATT;
#pragma unroll
    for (int i = 0; i < 4; ++i) ctx[i * 256 + tid] = 0.0f;
}

// ---- context[b][e] = sum_s w[b][s] * enc[b][s][e] ----
__global__ void k_context(const float* __restrict__ enc, const float* __restrict__ wgt,
                          float* __restrict__ ctx) {
    int sx = blockIdx.x, b = blockIdx.y, tid = threadIdx.x;  // grid (16,32), 256 thr
    __shared__ float wsh[128];
    if (tid < 128) wsh[tid] = wgt[(size_t)b * S_LEN + sx * 128 + tid];
    __syncthreads();
    const float* ep = enc + ((size_t)b * S_LEN + sx * 128) * ENC2 + tid * 4;
    float ax = 0, ay = 0, az = 0, aw = 0;
#pragma unroll 4
    for (int s = 0; s < 128; ++s) {
        float4 e = *(const float4*)(ep + (size_t)s * ENC2);
        float w = wsh[s];
        ax = fmaf(w, e.x, ax); ay = fmaf(w, e.y, ay);
        az = fmaf(w, e.z, az); aw = fmaf(w, e.w, aw);
    }
    float* c = ctx + (size_t)b * ATT + tid * 4;
    atomicAdd(c + 0, ax); atomicAdd(c + 1, ay);
    atomicAdd(c + 2, az); atomicAdd(c + 3, aw);
}

extern "C" void kernel_launch(void* const* d_in, const int* in_sizes, int n_in,
                              void* d_out, int out_size, void* d_ws, size_t ws_size,
                              hipStream_t stream) {
    (void)in_sizes; (void)n_in; (void)out_size; (void)ws_size;
    const float* dec   = (const float*)d_in[0];
    const float* enc   = (const float*)d_in[1];
    const int*   mask  = (const int*)d_in[2];
    const float* W_enc = (const float*)d_in[3];
    const float* b_enc = (const float*)d_in[4];
    const float* W_dec = (const float*)d_in[5];
    const float* b_dec = (const float*)d_in[6];
    const float* w_e   = (const float*)d_in[7];
    const float* b_e   = (const float*)d_in[8];

    float* out = (float*)d_out;
    unsigned short* WT = (unsigned short*)d_ws;
    float* dp = (float*)((char*)d_ws + DP_OFF);
    float* energy = out + BATCH * ATT;     // weights region doubles as energy scratch

    k_wt<<<dim3(32, 32), dim3(32, 8), 0, stream>>>(W_enc, WT);
    k_dproj<<<dim3(4, 32), 256, 0, stream>>>(dec, W_dec, b_dec, b_enc, dp);
    k_energy<<<1024, 512, 0, stream>>>(enc, (const short*)WT, dp, w_e, b_e, mask, energy);
    k_softmax<<<32, 256, 0, stream>>>(out);
    k_context<<<dim3(16, 32), 256, 0, stream>>>(enc, energy, out);
}

// Round 4
// 640.846 us; speedup vs baseline: 1.2152x; 1.2152x over previous
//
#include <hip/hip_runtime.h>
#include <math.h>

#define S_LEN 2048
#define ENC2  1024
#define DEC_H 1024
#define ATT   1024
#define BATCH 32

typedef __attribute__((ext_vector_type(8)))  short short8;
typedef __attribute__((ext_vector_type(16))) float f32x16;

// ws layout: packed B bf16 [64 kb][32 nb][64 lane][8] at 0 (2 MB),
//            dproj f32 [B][ATT] at 2 MB (128 KB)
#define DP_OFF (ATT * ENC2 * 2)

__device__ __forceinline__ unsigned short f2bf(float f) {
    unsigned int u = __float_as_uint(f);
    return (unsigned short)((u + 0x7FFFu + ((u >> 16) & 1u)) >> 16);  // RNE
}

__device__ __forceinline__ float tanh_fast(float x) {
    float ax = fabsf(x);
    float e = __expf(-2.0f * ax);
    float t = (1.0f - e) / (1.0f + e);
    return copysignf(t, x);
}

// ---- fragment-pack W_enc -> P[kb][nb][lane][j] = bf16(W[kb*16+(l>>5)*8+j][nb*32+(l&31)])
// One wave B-fragment (kb,nb) = contiguous 1 KB, 16 B per lane.
__global__ void k_pack(const float* __restrict__ W, unsigned short* __restrict__ P) {
    int t  = threadIdx.x;                 // 256
    int kb = blockIdx.x;                  // 64
    int nb = blockIdx.y * 4 + (t >> 6);   // 32
    int l  = t & 63;
    int n  = nb * 32 + (l & 31);
    int k0 = kb * 16 + ((l >> 5) * 8);
    short8 v;
#pragma unroll
    for (int j = 0; j < 8; ++j)
        v[j] = (short)f2bf(W[(size_t)(k0 + j) * ATT + n]);
    *(short8*)(P + (((size_t)kb * 32 + nb) * 64 + l) * 8) = v;
}

// ---- dproj[b][n] = dec[b]@W_dec[:,n] + b_dec[n] + b_enc[n] (f32 exact) ----
__global__ void k_dproj(const float* __restrict__ dec, const float* __restrict__ Wd,
                        const float* __restrict__ b_dec, const float* __restrict__ b_enc,
                        float* __restrict__ dp) {
    int n = blockIdx.x * 256 + threadIdx.x;
    int b = blockIdx.y;
    float acc = b_dec[n] + b_enc[n];
    const float* dh = dec + b * DEC_H;
#pragma unroll 16
    for (int k = 0; k < DEC_H; ++k)
        acc = fmaf(dh[k], Wd[(size_t)k * ATT + n], acc);
    dp[b * ATT + n] = acc;
}

// ---- energy[m] = w_e . tanh(enc[m]@W_enc + dproj[b]) + b_e ; mask ----
__launch_bounds__(512, 2)
__global__ void k_energy(const float* __restrict__ enc,          // [B*S][ENC2] f32
                         const short* __restrict__ BP,           // packed B
                         const float* __restrict__ dp,           // [B][ATT]
                         const float* __restrict__ w_e,
                         const float* __restrict__ b_e,
                         const int* __restrict__ mask,           // [B*S] bool->int32
                         float* __restrict__ energy)             // [B*S]
{
    __shared__ short As[64 * 1024];   // 128 KB bf16, XOR-swizzled
    float* e_lds = (float*)As;        // aliased: used only AFTER the MFMA loop

    const int tid = threadIdx.x;
    const int r0  = blockIdx.x * 64;
    const int b   = r0 >> 11;

    // stage A-tile: 64 rows x 1024 f32 -> bf16, swizzle byte^=((row&15)<<4)
    {
        const float* src = enc + (size_t)r0 * ENC2;
        char* smem = (char*)As;
        for (int u = tid; u < 8192; u += 512) {
            int row = u >> 7, slot = u & 127;
            const float* p = src + (size_t)row * ENC2 + slot * 8;
            float4 f0 = *(const float4*)p;
            float4 f1 = *(const float4*)(p + 4);
            short8 v;
            v[0] = (short)f2bf(f0.x); v[1] = (short)f2bf(f0.y);
            v[2] = (short)f2bf(f0.z); v[3] = (short)f2bf(f0.w);
            v[4] = (short)f2bf(f1.x); v[5] = (short)f2bf(f1.y);
            v[6] = (short)f2bf(f1.z); v[7] = (short)f2bf(f1.w);
            int dst = row * 2048 + ((slot * 16) ^ ((row & 15) << 4));
            *(short8*)(smem + dst) = v;
        }
    }
    __syncthreads();

    const int lane = tid & 63;
    const int wid  = tid >> 6;
    const int col  = lane & 31;
    const int hi   = lane >> 5;
    const int nw   = wid * 128;

    float dv[4], wv[4];
#pragma unroll
    for (int nf = 0; nf < 4; ++nf) {
        int n = nw + nf * 32 + col;
        dv[nf] = dp[b * ATT + n];
        wv[nf] = w_e[n];
    }

    f32x16 acc[2][4] = {};
    const int xr = (col & 15) << 4;
    const char* arow0 = (const char*)As + col * 2048;
    const char* arow1 = (const char*)As + (col + 32) * 2048;

    // B: fragment (kb, nb=wid*4+nf) at BP + kb*32768 + nb*1024, lane*16
    const char* bp = (const char*)BP + (size_t)(wid * 4) * 1024 + lane * 16;

    short8 b0[4], b1[4];
#pragma unroll
    for (int nf = 0; nf < 4; ++nf) b0[nf] = *(const short8*)(bp + nf * 1024);
#pragma unroll
    for (int nf = 0; nf < 4; ++nf) b1[nf] = *(const short8*)(bp + 32768 + nf * 1024);

    for (int kb = 0; kb < 64; kb += 2) {
        // ---- body A: consume b0 (k-block kb), then refill b0 from kb+2 ----
        {
            int off = ((kb * 32 + hi * 16) ^ xr);
            short8 a0 = *(const short8*)(arow0 + off);
            short8 a1 = *(const short8*)(arow1 + off);
#pragma unroll
            for (int nf = 0; nf < 4; ++nf) {
                acc[0][nf] = __builtin_amdgcn_mfma_f32_32x32x16_bf16(a0, b0[nf], acc[0][nf], 0, 0, 0);
                acc[1][nf] = __builtin_amdgcn_mfma_f32_32x32x16_bf16(a1, b0[nf], acc[1][nf], 0, 0, 0);
            }
            const char* pf = bp + (size_t)(kb + 2 < 64 ? kb + 2 : kb) * 32768;
#pragma unroll
            for (int nf = 0; nf < 4; ++nf) b0[nf] = *(const short8*)(pf + nf * 1024);
        }
        // ---- body B: consume b1 (k-block kb+1), then refill b1 from kb+3 ----
        {
            int off = (((kb + 1) * 32 + hi * 16) ^ xr);
            short8 a0 = *(const short8*)(arow0 + off);
            short8 a1 = *(const short8*)(arow1 + off);
#pragma unroll
            for (int nf = 0; nf < 4; ++nf) {
                acc[0][nf] = __builtin_amdgcn_mfma_f32_32x32x16_bf16(a0, b1[nf], acc[0][nf], 0, 0, 0);
                acc[1][nf] = __builtin_amdgcn_mfma_f32_32x32x16_bf16(a1, b1[nf], acc[1][nf], 0, 0, 0);
            }
            const char* pf = bp + (size_t)(kb + 3 < 64 ? kb + 3 : kb) * 32768;
#pragma unroll
            for (int nf = 0; nf < 4; ++nf) b1[nf] = *(const short8*)(pf + nf * 1024);
        }
    }

    // epilogue: tanh, dot with w_e, per-lane partials over 32 rows
    float ep[32];
#pragma unroll
    for (int mf = 0; mf < 2; ++mf)
#pragma unroll
        for (int reg = 0; reg < 16; ++reg) {
            float s = 0.0f;
#pragma unroll
            for (int nf = 0; nf < 4; ++nf)
                s = fmaf(wv[nf], tanh_fast(acc[mf][nf][reg] + dv[nf]), s);
            ep[mf * 16 + reg] = s;
        }

#pragma unroll
    for (int d = 1; d < 32; d <<= 1)
#pragma unroll
        for (int j = 0; j < 32; ++j)
            ep[j] += __shfl_xor(ep[j], d, 64);

    __syncthreads();                       // all waves done reading As
    if (tid < 64) e_lds[tid] = 0.0f;
    __syncthreads();

    if (col == 0) {
#pragma unroll
        for (int j = 0; j < 32; ++j) {
            int reg = j & 15;
            int row = (j >> 4) * 32 + (reg & 3) + 8 * (reg >> 2) + 4 * hi;
            atomicAdd(&e_lds[row], ep[j]);
        }
    }
    __syncthreads();

    if (tid < 64) {
        int m = r0 + tid;                    // m = b*S + s (flat)
        float e = e_lds[tid] + b_e[0];
        if (!mask[m]) e = -INFINITY;         // mask is int32 (bool -> int)
        energy[m] = e;
    }
}

// ---- softmax over S per batch, in place; also zero context region ----
__global__ void k_softmax(float* __restrict__ out) {
    int b = blockIdx.x, tid = threadIdx.x;   // 256 threads
    float* ew = out + BATCH * ATT + (size_t)b * S_LEN;
    float v[8];
#pragma unroll
    for (int i = 0; i < 8; ++i) v[i] = ew[i * 256 + tid];
    float m = v[0];
#pragma unroll
    for (int i = 1; i < 8; ++i) m = fmaxf(m, v[i]);
#pragma unroll
    for (int d = 1; d < 64; d <<= 1) m = fmaxf(m, __shfl_xor(m, d, 64));
    __shared__ float red[4], red2[4];
    int w = tid >> 6;
    if ((tid & 63) == 0) red[w] = m;
    __syncthreads();
    m = fmaxf(fmaxf(red[0], red[1]), fmaxf(red[2], red[3]));
    float s = 0.0f;
#pragma unroll
    for (int i = 0; i < 8; ++i) { v[i] = __expf(v[i] - m); s += v[i]; }
#pragma unroll
    for (int d = 1; d < 64; d <<= 1) s += __shfl_xor(s, d, 64);
    if ((tid & 63) == 0) red2[w] = s;
    __syncthreads();
    s = red2[0] + red2[1] + red2[2] + red2[3];
    float inv = 1.0f / s;
#pragma unroll
    for (int i = 0; i < 8; ++i) ew[i * 256 + tid] = v[i] * inv;
    float* ctx = out + (size_t)b * ATT;
#pragma unroll
    for (int i = 0; i < 4; ++i) ctx[i * 256 + tid] = 0.0f;
}

// ---- context[b][e] = sum_s w[b][s] * enc[b][s][e] ----
__global__ void k_context(const float* __restrict__ enc, const float* __restrict__ wgt,
                          float* __restrict__ ctx) {
    int sx = blockIdx.x, b = blockIdx.y, tid = threadIdx.x;  // grid (16,32), 256 thr
    __shared__ float wsh[128];
    if (tid < 128) wsh[tid] = wgt[(size_t)b * S_LEN + sx * 128 + tid];
    __syncthreads();
    const float* ep = enc + ((size_t)b * S_LEN + sx * 128) * ENC2 + tid * 4;
    float ax = 0, ay = 0, az = 0, aw = 0;
#pragma unroll 4
    for (int s = 0; s < 128; ++s) {
        float4 e = *(const float4*)(ep + (size_t)s * ENC2);
        float w = wsh[s];
        ax = fmaf(w, e.x, ax); ay = fmaf(w, e.y, ay);
        az = fmaf(w, e.z, az); aw = fmaf(w, e.w, aw);
    }
    float* c = ctx + (size_t)b * ATT + tid * 4;
    atomicAdd(c + 0, ax); atomicAdd(c + 1, ay);
    atomicAdd(c + 2, az); atomicAdd(c + 3, aw);
}

extern "C" void kernel_launch(void* const* d_in, const int* in_sizes, int n_in,
                              void* d_out, int out_size, void* d_ws, size_t ws_size,
                              hipStream_t stream) {
    (void)in_sizes; (void)n_in; (void)out_size; (void)ws_size;
    const float* dec   = (const float*)d_in[0];
    const float* enc   = (const float*)d_in[1];
    const int*   mask  = (const int*)d_in[2];
    const float* W_enc = (const float*)d_in[3];
    const float* b_enc = (const float*)d_in[4];
    const float* W_dec = (const float*)d_in[5];
    const float* b_dec = (const float*)d_in[6];
    const float* w_e   = (const float*)d_in[7];
    const float* b_e   = (const float*)d_in[8];

    float* out = (float*)d_out;
    unsigned short* BP = (unsigned short*)d_ws;
    float* dp = (float*)((char*)d_ws + DP_OFF);
    float* energy = out + BATCH * ATT;     // weights region doubles as energy scratch

    k_pack<<<dim3(64, 8), 256, 0, stream>>>(W_enc, BP);
    k_dproj<<<dim3(4, 32), 256, 0, stream>>>(dec, W_dec, b_dec, b_enc, dp);
    k_energy<<<1024, 512, 0, stream>>>(enc, (const short*)BP, dp, w_e, b_e, mask, energy);
    k_softmax<<<32, 256, 0, stream>>>(out);
    k_context<<<dim3(16, 32), 256, 0, stream>>>(enc, energy, out);
}

// Round 5
// 632.397 us; speedup vs baseline: 1.2314x; 1.0134x over previous
//
#include <hip/hip_runtime.h>
#include <math.h>

#define S_LEN 2048
#define ENC2  1024
#define DEC_H 1024
#define ATT   1024
#define BATCH 32

typedef __attribute__((ext_vector_type(8)))  short short8;
typedef __attribute__((ext_vector_type(16))) float f32x16;

// ws layout: packed B bf16 [64 kb][32 nb][64 lane][8] at 0 (2 MB),
//            dproj f32 [B][ATT] at 2 MB (128 KB)
#define DP_OFF (ATT * ENC2 * 2)

__device__ __forceinline__ unsigned short f2bf(float f) {
    unsigned int u = __float_as_uint(f);
    return (unsigned short)((u + 0x7FFFu + ((u >> 16) & 1u)) >> 16);  // RNE
}

__device__ __forceinline__ float tanh_fast(float x) {
    float ax = fabsf(x);
    float e = __expf(-2.0f * ax);
    float t = (1.0f - e) / (1.0f + e);
    return copysignf(t, x);
}

// ---- fragment-pack W_enc -> P[kb][nb][lane][j] = bf16(W[kb*16+(l>>5)*8+j][nb*32+(l&31)])
__global__ void k_pack(const float* __restrict__ W, unsigned short* __restrict__ P) {
    int t  = threadIdx.x;                 // 256
    int kb = blockIdx.x;                  // 64
    int nb = blockIdx.y * 4 + (t >> 6);   // 32
    int l  = t & 63;
    int n  = nb * 32 + (l & 31);
    int k0 = kb * 16 + ((l >> 5) * 8);
    short8 v;
#pragma unroll
    for (int j = 0; j < 8; ++j)
        v[j] = (short)f2bf(W[(size_t)(k0 + j) * ATT + n]);
    *(short8*)(P + (((size_t)kb * 32 + nb) * 64 + l) * 8) = v;
}

// ---- dproj[b][n] = dec[b]@W_dec[:,n] + b_dec[n] + b_enc[n] (f32, 4-way ILP) ----
__global__ void k_dproj(const float* __restrict__ dec, const float* __restrict__ Wd,
                        const float* __restrict__ b_dec, const float* __restrict__ b_enc,
                        float* __restrict__ dp) {
    int n = blockIdx.x * 256 + threadIdx.x;
    int b = blockIdx.y;
    const float* dh = dec + b * DEC_H;
    float a0 = 0, a1 = 0, a2 = 0, a3 = 0;
#pragma unroll 8
    for (int k = 0; k < DEC_H; k += 4) {
        a0 = fmaf(dh[k + 0], Wd[(size_t)(k + 0) * ATT + n], a0);
        a1 = fmaf(dh[k + 1], Wd[(size_t)(k + 1) * ATT + n], a1);
        a2 = fmaf(dh[k + 2], Wd[(size_t)(k + 2) * ATT + n], a2);
        a3 = fmaf(dh[k + 3], Wd[(size_t)(k + 3) * ATT + n], a3);
    }
    dp[b * ATT + n] = b_dec[n] + b_enc[n] + ((a0 + a1) + (a2 + a3));
}

// ---- energy: persistent blocks, 4 tiles x 4 K-quarter phases, dbuf LDS ----
__launch_bounds__(512, 2)
__global__ void k_energy(const float* __restrict__ enc,          // [B*S][ENC2] f32
                         const short* __restrict__ BP,           // packed B (2 MB)
                         const float* __restrict__ dp,           // [B][ATT]
                         const float* __restrict__ w_e,
                         const float* __restrict__ b_e,
                         const int* __restrict__ mask,           // [B*S] bool->int32
                         float* __restrict__ energy)             // [B*S]
{
    __shared__ short As[2][64][256];   // 2 x 32 KB K-quarter buffers, XOR-swizzled
    __shared__ float e_lds[64];

    const int tid    = threadIdx.x;
    const int bid    = blockIdx.x;        // 256 blocks, 1 per CU
    const int rowblk = bid * 256;         // this block's 256 rows (4 tiles of 64)
    const int b      = rowblk >> 11;      // whole block inside one batch

    const int lane = tid & 63;
    const int wid  = tid >> 6;
    const int col  = lane & 31;
    const int hi   = lane >> 5;
    const int hi16 = hi * 16;
    const int xr   = (col & 15) << 4;

    // staging mapping: thread -> (row, 32-float chunk)
    const int srow  = tid >> 3;           // 0..63
    const int schk  = tid & 7;            // 0..7
    const int sw    = (srow & 15) << 4;

    float dv[4], wv[4];
#pragma unroll
    for (int nf = 0; nf < 4; ++nf) {
        int n = wid * 128 + nf * 32 + col;
        dv[nf] = dp[b * ATT + n];
        wv[nf] = w_e[n];
    }

    const char* bpp = (const char*)BP + (wid << 12) + lane * 16;

    f32x16 acc[2][4];
#pragma unroll
    for (int mf = 0; mf < 2; ++mf)
#pragma unroll
        for (int nf = 0; nf < 4; ++nf)
#pragma unroll
            for (int r = 0; r < 16; ++r) acc[mf][nf][r] = 0.0f;

    short8 bb0[4], bb1[4];
#pragma unroll
    for (int nf = 0; nf < 4; ++nf) bb0[nf] = *(const short8*)(bpp + nf * 1024);
#pragma unroll
    for (int nf = 0; nf < 4; ++nf) bb1[nf] = *(const short8*)(bpp + 32768 + nf * 1024);

    // ---- prologue: stage quarter 0 into As[0] ----
    {
        const float* src = enc + ((size_t)(rowblk + srow) << 10) + schk * 32;
        float4 f[8];
#pragma unroll
        for (int i = 0; i < 8; ++i) f[i] = ((const float4*)src)[i];
        char* dst = (char*)&As[0][0][0] + srow * 512;
#pragma unroll
        for (int j = 0; j < 4; ++j) {
            float4 f0 = f[2 * j], f1 = f[2 * j + 1];
            short8 v;
            v[0] = (short)f2bf(f0.x); v[1] = (short)f2bf(f0.y);
            v[2] = (short)f2bf(f0.z); v[3] = (short)f2bf(f0.w);
            v[4] = (short)f2bf(f1.x); v[5] = (short)f2bf(f1.y);
            v[6] = (short)f2bf(f1.z); v[7] = (short)f2bf(f1.w);
            *(short8*)(dst + ((schk * 64 + j * 16) ^ sw)) = v;
        }
        __syncthreads();
    }

#pragma unroll 1
    for (int q = 0; q < 16; ++q) {       // global quarter index: tile = q>>2
        // ---- issue next quarter's global loads (hidden under compute) ----
        float4 f[8];
        const bool have = (q < 15);
        if (have) {
            const int qq = q + 1;
            const float* src = enc + ((size_t)(rowblk + ((qq >> 2) << 6) + srow) << 10)
                                   + ((qq & 3) << 8) + schk * 32;
#pragma unroll
            for (int i = 0; i < 8; ++i) f[i] = ((const float4*)src)[i];
        }

        // ---- compute 16 k-steps on As[q&1]; B rotates continuously ----
        const char* ab    = (const char*)&As[0][0][0] + ((q & 1) << 15);
        const char* arow0 = ab + col * 512;
        const char* arow1 = ab + (col + 32) * 512;
#pragma unroll
        for (int t = 0; t < 16; t += 2) {
            const int kb = (q << 4) + t;
            {
                int o0 = (t * 32 + hi16) ^ xr;
                short8 a0 = *(const short8*)(arow0 + o0);
                short8 a1 = *(const short8*)(arow1 + o0);
#pragma unroll
                for (int nf = 0; nf < 4; ++nf) {
                    acc[0][nf] = __builtin_amdgcn_mfma_f32_32x32x16_bf16(a0, bb0[nf], acc[0][nf], 0, 0, 0);
                    acc[1][nf] = __builtin_amdgcn_mfma_f32_32x32x16_bf16(a1, bb0[nf], acc[1][nf], 0, 0, 0);
                }
                size_t ro = (size_t)((kb + 2) & 63) << 15;
#pragma unroll
                for (int nf = 0; nf < 4; ++nf) bb0[nf] = *(const short8*)(bpp + ro + nf * 1024);
            }
            {
                int o1 = ((t + 1) * 32 + hi16) ^ xr;
                short8 a0 = *(const short8*)(arow0 + o1);
                short8 a1 = *(const short8*)(arow1 + o1);
#pragma unroll
                for (int nf = 0; nf < 4; ++nf) {
                    acc[0][nf] = __builtin_amdgcn_mfma_f32_32x32x16_bf16(a0, bb1[nf], acc[0][nf], 0, 0, 0);
                    acc[1][nf] = __builtin_amdgcn_mfma_f32_32x32x16_bf16(a1, bb1[nf], acc[1][nf], 0, 0, 0);
                }
                size_t ro = (size_t)((kb + 3) & 63) << 15;
#pragma unroll
                for (int nf = 0; nf < 4; ++nf) bb1[nf] = *(const short8*)(bpp + ro + nf * 1024);
            }
        }

        __syncthreads();                 // all reads of As[(q+1)&1] finished (phase q-1)
        if (have) {
            char* dst = (char*)&As[0][0][0] + (((q + 1) & 1) << 15) + srow * 512;
#pragma unroll
            for (int j = 0; j < 4; ++j) {
                float4 f0 = f[2 * j], f1 = f[2 * j + 1];
                short8 v;
                v[0] = (short)f2bf(f0.x); v[1] = (short)f2bf(f0.y);
                v[2] = (short)f2bf(f0.z); v[3] = (short)f2bf(f0.w);
                v[4] = (short)f2bf(f1.x); v[5] = (short)f2bf(f1.y);
                v[6] = (short)f2bf(f1.z); v[7] = (short)f2bf(f1.w);
                *(short8*)(dst + ((schk * 64 + j * 16) ^ sw)) = v;
            }
        }
        __syncthreads();                 // As[(q+1)&1] ready

        // ---- tile epilogue ----
        if ((q & 3) == 3) {
            const int r0 = rowblk + ((q >> 2) << 6);
            float ep[32];
#pragma unroll
            for (int mf = 0; mf < 2; ++mf)
#pragma unroll
                for (int reg = 0; reg < 16; ++reg) {
                    float s = 0.0f;
#pragma unroll
                    for (int nf = 0; nf < 4; ++nf)
                        s = fmaf(wv[nf], tanh_fast(acc[mf][nf][reg] + dv[nf]), s);
                    ep[mf * 16 + reg] = s;
                }
#pragma unroll
            for (int d = 1; d < 32; d <<= 1)
#pragma unroll
                for (int j = 0; j < 32; ++j)
                    ep[j] += __shfl_xor(ep[j], d, 64);

            if (tid < 64) e_lds[tid] = 0.0f;
            __syncthreads();
            if (col == 0) {
#pragma unroll
                for (int j = 0; j < 32; ++j) {
                    int reg = j & 15;
                    int row = (j >> 4) * 32 + (reg & 3) + 8 * (reg >> 2) + 4 * hi;
                    atomicAdd(&e_lds[row], ep[j]);
                }
            }
            __syncthreads();
            if (tid < 64) {
                int m = r0 + tid;
                float e = e_lds[tid] + b_e[0];
                if (!mask[m]) e = -INFINITY;
                energy[m] = e;
            }
#pragma unroll
            for (int mf = 0; mf < 2; ++mf)
#pragma unroll
                for (int nf = 0; nf < 4; ++nf)
#pragma unroll
                    for (int r = 0; r < 16; ++r) acc[mf][nf][r] = 0.0f;
        }
    }
}

// ---- softmax over S per batch, in place; also zero context region ----
__global__ void k_softmax(float* __restrict__ out) {
    int b = blockIdx.x, tid = threadIdx.x;   // 256 threads
    float* ew = out + BATCH * ATT + (size_t)b * S_LEN;
    float v[8];
#pragma unroll
    for (int i = 0; i < 8; ++i) v[i] = ew[i * 256 + tid];
    float m = v[0];
#pragma unroll
    for (int i = 1; i < 8; ++i) m = fmaxf(m, v[i]);
#pragma unroll
    for (int d = 1; d < 64; d <<= 1) m = fmaxf(m, __shfl_xor(m, d, 64));
    __shared__ float red[4], red2[4];
    int w = tid >> 6;
    if ((tid & 63) == 0) red[w] = m;
    __syncthreads();
    m = fmaxf(fmaxf(red[0], red[1]), fmaxf(red[2], red[3]));
    float s = 0.0f;
#pragma unroll
    for (int i = 0; i < 8; ++i) { v[i] = __expf(v[i] - m); s += v[i]; }
#pragma unroll
    for (int d = 1; d < 64; d <<= 1) s += __shfl_xor(s, d, 64);
    if ((tid & 63) == 0) red2[w] = s;
    __syncthreads();
    s = red2[0] + red2[1] + red2[2] + red2[3];
    float inv = 1.0f / s;
#pragma unroll
    for (int i = 0; i < 8; ++i) ew[i * 256 + tid] = v[i] * inv;
    float* ctx = out + (size_t)b * ATT;
#pragma unroll
    for (int i = 0; i < 4; ++i) ctx[i * 256 + tid] = 0.0f;
}

// ---- context[b][e] = sum_s w[b][s] * enc[b][s][e] : 8-deep load batches ----
__global__ void k_context(const float* __restrict__ enc, const float* __restrict__ wgt,
                          float* __restrict__ ctx) {
    int sx = blockIdx.x, b = blockIdx.y, tid = threadIdx.x;  // grid (16,32), 256 thr
    __shared__ float wsh[128];
    if (tid < 128) wsh[tid] = wgt[(size_t)b * S_LEN + sx * 128 + tid];
    __syncthreads();
    const float* ep = enc + ((size_t)b * S_LEN + sx * 128) * ENC2 + tid * 4;
    float ax = 0, ay = 0, az = 0, aw = 0;
    for (int s0 = 0; s0 < 128; s0 += 8) {
        float4 r[8];
#pragma unroll
        for (int j = 0; j < 8; ++j)
            r[j] = *(const float4*)(ep + (size_t)(s0 + j) * ENC2);
#pragma unroll
        for (int j = 0; j < 8; ++j) {
            float w = wsh[s0 + j];
            ax = fmaf(w, r[j].x, ax); ay = fmaf(w, r[j].y, ay);
            az = fmaf(w, r[j].z, az); aw = fmaf(w, r[j].w, aw);
        }
    }
    float* c = ctx + (size_t)b * ATT + tid * 4;
    atomicAdd(c + 0, ax); atomicAdd(c + 1, ay);
    atomicAdd(c + 2, az); atomicAdd(c + 3, aw);
}

extern "C" void kernel_launch(void* const* d_in, const int* in_sizes, int n_in,
                              void* d_out, int out_size, void* d_ws, size_t ws_size,
                              hipStream_t stream) {
    (void)in_sizes; (void)n_in; (void)out_size; (void)ws_size;
    const float* dec   = (const float*)d_in[0];
    const float* enc   = (const float*)d_in[1];
    const int*   mask  = (const int*)d_in[2];
    const float* W_enc = (const float*)d_in[3];
    const float* b_enc = (const float*)d_in[4];
    const float* W_dec = (const float*)d_in[5];
    const float* b_dec = (const float*)d_in[6];
    const float* w_e   = (const float*)d_in[7];
    const float* b_e   = (const float*)d_in[8];

    float* out = (float*)d_out;
    unsigned short* BP = (unsigned short*)d_ws;
    float* dp = (float*)((char*)d_ws + DP_OFF);
    float* energy = out + BATCH * ATT;     // weights region doubles as energy scratch

    k_pack<<<dim3(64, 8), 256, 0, stream>>>(W_enc, BP);
    k_dproj<<<dim3(4, 32), 256, 0, stream>>>(dec, W_dec, b_dec, b_enc, dp);
    k_energy<<<256, 512, 0, stream>>>(enc, (const short*)BP, dp, w_e, b_e, mask, energy);
    k_softmax<<<32, 256, 0, stream>>>(out);
    k_context<<<dim3(16, 32), 256, 0, stream>>>(enc, energy, out);
}

// Round 6
// 574.139 us; speedup vs baseline: 1.3564x; 1.1015x over previous
//
#include <hip/hip_runtime.h>
#include <math.h>

#define S_LEN 2048
#define ENC2  1024
#define DEC_H 1024
#define ATT   1024
#define BATCH 32

typedef __attribute__((ext_vector_type(8)))  short short8;
typedef __attribute__((ext_vector_type(4)))  short s4;
typedef __attribute__((ext_vector_type(16))) float f32x16;

// ws layout: packed B bf16 [64 kb][32 nb][64 lane][8] at 0 (2 MB),
//            dproj f32 [B][ATT] at 2 MB (128 KB)
#define DP_OFF (ATT * ENC2 * 2)

__device__ __forceinline__ unsigned short f2bf(float f) {
    unsigned int u = __float_as_uint(f);
    return (unsigned short)((u + 0x7FFFu + ((u >> 16) & 1u)) >> 16);  // RNE
}

__device__ __forceinline__ float tanh_fast(float x) {
    float ax = fabsf(x);
    float e = __expf(-2.0f * ax);
    float t = (1.0f - e) / (1.0f + e);
    return copysignf(t, x);
}

// ---- fragment-pack W_enc -> P[kb][nb][lane][j] = bf16(W[kb*16+(l>>5)*8+j][nb*32+(l&31)])
__global__ void k_pack(const float* __restrict__ W, unsigned short* __restrict__ P) {
    int t  = threadIdx.x;                 // 256
    int kb = blockIdx.x;                  // 64
    int nb = blockIdx.y * 4 + (t >> 6);   // 32
    int l  = t & 63;
    int n  = nb * 32 + (l & 31);
    int k0 = kb * 16 + ((l >> 5) * 8);
    short8 v;
#pragma unroll
    for (int j = 0; j < 8; ++j)
        v[j] = (short)f2bf(W[(size_t)(k0 + j) * ATT + n]);
    *(short8*)(P + (((size_t)kb * 32 + nb) * 64 + l) * 8) = v;
}

// ---- dproj[b][n] = dec[b]@W_dec[:,n] + b_dec[n] + b_enc[n] (f32, 4-way ILP) ----
__global__ void k_dproj(const float* __restrict__ dec, const float* __restrict__ Wd,
                        const float* __restrict__ b_dec, const float* __restrict__ b_enc,
                        float* __restrict__ dp) {
    int n = blockIdx.x * 256 + threadIdx.x;
    int b = blockIdx.y;
    const float* dh = dec + b * DEC_H;
    float a0 = 0, a1 = 0, a2 = 0, a3 = 0;
#pragma unroll 8
    for (int k = 0; k < DEC_H; k += 4) {
        a0 = fmaf(dh[k + 0], Wd[(size_t)(k + 0) * ATT + n], a0);
        a1 = fmaf(dh[k + 1], Wd[(size_t)(k + 1) * ATT + n], a1);
        a2 = fmaf(dh[k + 2], Wd[(size_t)(k + 2) * ATT + n], a2);
        a3 = fmaf(dh[k + 3], Wd[(size_t)(k + 3) * ATT + n], a3);
    }
    dp[b * ATT + n] = b_dec[n] + b_enc[n] + ((a0 + a1) + (a2 + a3));
}

// ---- energy partials: 4096 blocks (1024 stripes x 4 N-quarters), 256 thr ----
// Each block: 64 rows x 256 cols x K=1024; atomicAdd 256-col partial into ew.
__launch_bounds__(256, 4)
__global__ void k_energy(const float* __restrict__ enc,   // [65536][1024] f32
                         const short* __restrict__ BP,    // packed B (2 MB)
                         const float* __restrict__ dp,    // [B][ATT]
                         const float* __restrict__ w_e,
                         float* __restrict__ ew)          // [B*S] raw partial sums
{
    __shared__ short As[2][64][64];   // 2 x 8 KB K-16th buffers, swizzle ^((row&7)<<4)
    __shared__ float e_lds[64];

    const int tid   = threadIdx.x;
    const int bid   = blockIdx.x;
    const int swz   = (bid & 7) * 512 + (bid >> 3);   // XCD-chunked: same-stripe
    const int stripe = swz >> 2;                      // quarters land on same XCD
    const int nq    = swz & 3;
    const int r0    = stripe << 6;
    const int b     = stripe >> 5;

    const int lane = tid & 63;
    const int wid  = tid >> 6;        // 0..3
    const int col  = lane & 31;
    const int hi   = lane >> 5;
    const int hi16 = hi << 4;
    const int xr   = (col & 7) << 4;  // rows col and col+32 share (row&7)

    float dv[2], wv[2];
#pragma unroll
    for (int nf = 0; nf < 2; ++nf) {
        int n = nq * 256 + wid * 64 + nf * 32 + col;
        dv[nf] = dp[b * ATT + n];
        wv[nf] = w_e[n];
    }

    // B fragment (kb, nb) at BP + kb*32768 + nb*1024 bytes; nb = nq*8 + wid*2 + nf
    const char* bpp = (const char*)BP + (size_t)(nq * 8 + wid * 2) * 1024 + lane * 16;

    f32x16 acc[2][2];
#pragma unroll
    for (int mf = 0; mf < 2; ++mf)
#pragma unroll
        for (int nf = 0; nf < 2; ++nf)
#pragma unroll
            for (int r = 0; r < 16; ++r) acc[mf][nf][r] = 0.0f;

    short8 bb0[2], bb1[2];
    bb0[0] = *(const short8*)(bpp);
    bb0[1] = *(const short8*)(bpp + 1024);
    bb1[0] = *(const short8*)(bpp + 32768);
    bb1[1] = *(const short8*)(bpp + 32768 + 1024);

    // ---- prologue: stage phase 0 (k 0..63) into As[0] ----
#pragma unroll
    for (int i = 0; i < 4; ++i) {
        int u = i * 256 + tid, row = u >> 4, fs = u & 15;
        float4 fv = *(const float4*)(enc + ((size_t)(r0 + row) << 10) + (fs << 2));
        s4 v; v[0] = (short)f2bf(fv.x); v[1] = (short)f2bf(fv.y);
              v[2] = (short)f2bf(fv.z); v[3] = (short)f2bf(fv.w);
        *(s4*)((char*)As + row * 128 + ((fs * 8) ^ ((row & 7) << 4))) = v;
    }
    __syncthreads();

#pragma unroll 1
    for (int ph = 0; ph < 16; ++ph) {
        // issue next phase's global loads early (hidden under compute)
        float4 f[4];
        const bool have = (ph < 15);
        if (have) {
#pragma unroll
            for (int i = 0; i < 4; ++i) {
                int u = i * 256 + tid, row = u >> 4, fs = u & 15;
                f[i] = *(const float4*)(enc + ((size_t)(r0 + row) << 10)
                                            + ((ph + 1) << 6) + (fs << 2));
            }
        }

        // compute 4 k-steps from As[ph&1]; B rotates continuously across phases
        const char* ab    = (const char*)As + ((ph & 1) << 13);
        const char* arow0 = ab + col * 128;
        const char* arow1 = ab + (col + 32) * 128;
        const int kbase = ph << 2;
#pragma unroll
        for (int t = 0; t < 4; t += 2) {
            {
                int off = ((t << 5) + hi16) ^ xr;
                short8 a0 = *(const short8*)(arow0 + off);
                short8 a1 = *(const short8*)(arow1 + off);
                acc[0][0] = __builtin_amdgcn_mfma_f32_32x32x16_bf16(a0, bb0[0], acc[0][0], 0, 0, 0);
                acc[0][1] = __builtin_amdgcn_mfma_f32_32x32x16_bf16(a0, bb0[1], acc[0][1], 0, 0, 0);
                acc[1][0] = __builtin_amdgcn_mfma_f32_32x32x16_bf16(a1, bb0[0], acc[1][0], 0, 0, 0);
                acc[1][1] = __builtin_amdgcn_mfma_f32_32x32x16_bf16(a1, bb0[1], acc[1][1], 0, 0, 0);
                size_t ro = (size_t)((kbase + t + 2) & 63) << 15;
                bb0[0] = *(const short8*)(bpp + ro);
                bb0[1] = *(const short8*)(bpp + ro + 1024);
            }
            {
                int off = (((t + 1) << 5) + hi16) ^ xr;
                short8 a0 = *(const short8*)(arow0 + off);
                short8 a1 = *(const short8*)(arow1 + off);
                acc[0][0] = __builtin_amdgcn_mfma_f32_32x32x16_bf16(a0, bb1[0], acc[0][0], 0, 0, 0);
                acc[0][1] = __builtin_amdgcn_mfma_f32_32x32x16_bf16(a0, bb1[1], acc[0][1], 0, 0, 0);
                acc[1][0] = __builtin_amdgcn_mfma_f32_32x32x16_bf16(a1, bb1[0], acc[1][0], 0, 0, 0);
                acc[1][1] = __builtin_amdgcn_mfma_f32_32x32x16_bf16(a1, bb1[1], acc[1][1], 0, 0, 0);
                size_t ro = (size_t)((kbase + t + 3) & 63) << 15;
                bb1[0] = *(const short8*)(bpp + ro);
                bb1[1] = *(const short8*)(bpp + ro + 1024);
            }
        }

        __syncthreads();                  // readers done with As[(ph+1)&1]
        if (have) {
            char* dst = (char*)As + (((ph + 1) & 1) << 13);
#pragma unroll
            for (int i = 0; i < 4; ++i) {
                int u = i * 256 + tid, row = u >> 4, fs = u & 15;
                float4 fv = f[i];
                s4 v; v[0] = (short)f2bf(fv.x); v[1] = (short)f2bf(fv.y);
                      v[2] = (short)f2bf(fv.z); v[3] = (short)f2bf(fv.w);
                *(s4*)(dst + row * 128 + ((fs * 8) ^ ((row & 7) << 4))) = v;
            }
        }
        __syncthreads();
    }

    // ---- epilogue: tanh, dot w_e over this block's 256 cols, partial-add ----
    float ep[32];
#pragma unroll
    for (int mf = 0; mf < 2; ++mf)
#pragma unroll
        for (int reg = 0; reg < 16; ++reg) {
            float s = fmaf(wv[0], tanh_fast(acc[mf][0][reg] + dv[0]),
                           wv[1] * tanh_fast(acc[mf][1][reg] + dv[1]));
            ep[mf * 16 + reg] = s;
        }
#pragma unroll
    for (int d = 1; d < 32; d <<= 1)
#pragma unroll
        for (int j = 0; j < 32; ++j)
            ep[j] += __shfl_xor(ep[j], d, 64);

    if (tid < 64) e_lds[tid] = 0.0f;
    __syncthreads();
    if (col == 0) {
#pragma unroll
        for (int j = 0; j < 32; ++j) {
            int reg = j & 15;
            int row = (j >> 4) * 32 + (reg & 3) + 8 * (reg >> 2) + 4 * hi;
            atomicAdd(&e_lds[row], ep[j]);
        }
    }
    __syncthreads();
    if (tid < 64) atomicAdd(&ew[r0 + tid], e_lds[tid]);
}

// ---- softmax: bias + mask + softmax over S, in place; zero context region ----
__global__ void k_softmax(const int* __restrict__ mask, const float* __restrict__ b_e,
                          float* __restrict__ out) {
    int b = blockIdx.x, tid = threadIdx.x;   // 256 threads
    float* ew = out + BATCH * ATT + (size_t)b * S_LEN;
    const int* mk = mask + (size_t)b * S_LEN;
    float be = b_e[0];
    float v[8];
#pragma unroll
    for (int i = 0; i < 8; ++i) {
        int s = i * 256 + tid;
        float e = ew[s] + be;
        v[i] = mk[s] ? e : -INFINITY;
    }
    float m = v[0];
#pragma unroll
    for (int i = 1; i < 8; ++i) m = fmaxf(m, v[i]);
#pragma unroll
    for (int d = 1; d < 64; d <<= 1) m = fmaxf(m, __shfl_xor(m, d, 64));
    __shared__ float red[4], red2[4];
    int w = tid >> 6;
    if ((tid & 63) == 0) red[w] = m;
    __syncthreads();
    m = fmaxf(fmaxf(red[0], red[1]), fmaxf(red[2], red[3]));
    float s = 0.0f;
#pragma unroll
    for (int i = 0; i < 8; ++i) { v[i] = __expf(v[i] - m); s += v[i]; }
#pragma unroll
    for (int d = 1; d < 64; d <<= 1) s += __shfl_xor(s, d, 64);
    if ((tid & 63) == 0) red2[w] = s;
    __syncthreads();
    s = red2[0] + red2[1] + red2[2] + red2[3];
    float inv = 1.0f / s;
#pragma unroll
    for (int i = 0; i < 8; ++i) ew[i * 256 + tid] = v[i] * inv;
    float* ctx = out + (size_t)b * ATT;
#pragma unroll
    for (int i = 0; i < 4; ++i) ctx[i * 256 + tid] = 0.0f;
}

// ---- context[b][e] = sum_s w[b][s] * enc[b][s][e] : 8-deep load batches ----
__global__ void k_context(const float* __restrict__ enc, const float* __restrict__ wgt,
                          float* __restrict__ ctx) {
    int sx = blockIdx.x, b = blockIdx.y, tid = threadIdx.x;  // grid (32,32), 256 thr
    __shared__ float wsh[64];
    if (tid < 64) wsh[tid] = wgt[(size_t)b * S_LEN + sx * 64 + tid];
    __syncthreads();
    const float* ep = enc + ((size_t)b * S_LEN + sx * 64) * ENC2 + tid * 4;
    float ax = 0, ay = 0, az = 0, aw = 0;
    for (int s0 = 0; s0 < 64; s0 += 8) {
        float4 r[8];
#pragma unroll
        for (int j = 0; j < 8; ++j)
            r[j] = *(const float4*)(ep + (size_t)(s0 + j) * ENC2);
#pragma unroll
        for (int j = 0; j < 8; ++j) {
            float w = wsh[s0 + j];
            ax = fmaf(w, r[j].x, ax); ay = fmaf(w, r[j].y, ay);
            az = fmaf(w, r[j].z, az); aw = fmaf(w, r[j].w, aw);
        }
    }
    float* c = ctx + (size_t)b * ATT + tid * 4;
    atomicAdd(c + 0, ax); atomicAdd(c + 1, ay);
    atomicAdd(c + 2, az); atomicAdd(c + 3, aw);
}

extern "C" void kernel_launch(void* const* d_in, const int* in_sizes, int n_in,
                              void* d_out, int out_size, void* d_ws, size_t ws_size,
                              hipStream_t stream) {
    (void)in_sizes; (void)n_in; (void)out_size; (void)ws_size;
    const float* dec   = (const float*)d_in[0];
    const float* enc   = (const float*)d_in[1];
    const int*   mask  = (const int*)d_in[2];
    const float* W_enc = (const float*)d_in[3];
    const float* b_enc = (const float*)d_in[4];
    const float* W_dec = (const float*)d_in[5];
    const float* b_dec = (const float*)d_in[6];
    const float* w_e   = (const float*)d_in[7];
    const float* b_e   = (const float*)d_in[8];

    float* out = (float*)d_out;
    unsigned short* BP = (unsigned short*)d_ws;
    float* dp = (float*)((char*)d_ws + DP_OFF);
    float* ew = out + BATCH * ATT;     // weights region accumulates raw energy

    hipMemsetAsync(ew, 0, (size_t)BATCH * S_LEN * sizeof(float), stream);
    k_pack<<<dim3(64, 8), 256, 0, stream>>>(W_enc, BP);
    k_dproj<<<dim3(4, 32), 256, 0, stream>>>(dec, W_dec, b_dec, b_enc, dp);
    k_energy<<<4096, 256, 0, stream>>>(enc, (const short*)BP, dp, w_e, ew);
    k_softmax<<<32, 256, 0, stream>>>(mask, b_e, out);
    k_context<<<dim3(32, 32), 256, 0, stream>>>(enc, ew, out);
}